// Round 15
// baseline (425.181 us; speedup 1.0000x reference)
//
#include <hip/hip_runtime.h>

#define F_IN 144
typedef __attribute__((ext_vector_type(8))) short short8v;
typedef __attribute__((ext_vector_type(8))) unsigned short ushort8v;
typedef __attribute__((ext_vector_type(4))) float f32x4;
typedef unsigned short u16;

// ---------------- bf16 helpers ----------------
__device__ __forceinline__ u16 bf16rn(float x) {
    union { float f; unsigned u; } a; a.f = x;
    return (u16)((a.u + 0x7FFFu + ((a.u >> 16) & 1u)) >> 16);
}
__device__ __forceinline__ float bf16tof(u16 h) {
    union { float f; unsigned u; } a; a.u = ((unsigned)h) << 16;
    return a.f;
}
__device__ __forceinline__ void gload_lds16(const u16* g, u16* s) {
    __builtin_amdgcn_global_load_lds(
        (const __attribute__((address_space(1))) void*)g,
        (__attribute__((address_space(3))) void*)s, 16, 0, 0);
}

// ---------------- utility ----------------
__global__ void zero_i32(int* __restrict__ p, int n) {
    int i = blockIdx.x * blockDim.x + threadIdx.x;
    if (i < n) p[i] = 0;
}
__global__ void zero_f32(float* __restrict__ p, int n) {
    int i = blockIdx.x * blockDim.x + threadIdx.x;
    if (i < n) p[i] = 0.f;
}
// weights: f32 -> bf16 hi/lo (fp24)
__global__ void conv_hl(const float* __restrict__ src, u16* __restrict__ dh,
                        u16* __restrict__ dl, int n) {
    int i = blockIdx.x * 256 + threadIdx.x;
    if (i < n) {
        float v = src[i];
        u16 h = bf16rn(v);
        dh[i] = h;
        dl[i] = bf16rn(v - bf16tof(h));
    }
}
// f32 -> bf16 single plane
__global__ void conv_bf(const float* __restrict__ src, u16* __restrict__ d, int n) {
    int i = blockIdx.x * 256 + threadIdx.x;
    if (i < n) d[i] = bf16rn(src[i]);
}

// ---------------- CSR build ----------------
__global__ void count_edges(const int* __restrict__ dst, int* __restrict__ counts, int E) {
    int e = blockIdx.x * blockDim.x + threadIdx.x;
    if (e < E) atomicAdd(&counts[dst[e]], 1);
}

// 3-pass parallel exclusive scan (2048 elements per block)
#define SCB 2048
__global__ __launch_bounds__(256) void scan_partial(const int* __restrict__ counts,
                                                    int* __restrict__ rowptr,
                                                    int* __restrict__ bsum, int N) {
    __shared__ int ls[256];
    int t = threadIdx.x;
    int base = blockIdx.x * SCB + t * 8;
    int v[8]; int s = 0;
#pragma unroll
    for (int j = 0; j < 8; ++j) {
        int i = base + j;
        v[j] = (i < N) ? counts[i] : 0;
        s += v[j];
    }
    ls[t] = s;
    __syncthreads();
    for (int off = 1; off < 256; off <<= 1) {
        int x = (t >= off) ? ls[t - off] : 0;
        __syncthreads();
        ls[t] += x;
        __syncthreads();
    }
    int run = (t == 0) ? 0 : ls[t - 1];
#pragma unroll
    for (int j = 0; j < 8; ++j) {
        int i = base + j;
        if (i < N) rowptr[i] = run;
        run += v[j];
    }
    if (t == 255) bsum[blockIdx.x] = ls[255];
}

__global__ __launch_bounds__(256) void scan_tops(const int* __restrict__ bsum,
                                                 int* __restrict__ boff, int nb) {
    __shared__ int ls[256];
    int t = threadIdx.x;
    ls[t] = (t < nb) ? bsum[t] : 0;
    __syncthreads();
    for (int off = 1; off < 256; off <<= 1) {
        int x = (t >= off) ? ls[t - off] : 0;
        __syncthreads();
        ls[t] += x;
        __syncthreads();
    }
    boff[t] = (t == 0) ? 0 : ls[t - 1];   // exclusive block prefix
}

__global__ void scan_add(int* __restrict__ rowptr, int* __restrict__ fillhead,
                         const int* __restrict__ boff, int N, int E) {
    int i = blockIdx.x * 256 + threadIdx.x;
    if (i < N) {
        int r = rowptr[i] + boff[i >> 11];   // SCB = 2048 = 1<<11
        rowptr[i] = r;
        fillhead[i] = r;
    }
    if (i == N) rowptr[N] = E;
}

__global__ void fill_edges(const int* __restrict__ src, const int* __restrict__ dst,
                           const float* __restrict__ ea, int* __restrict__ fillhead,
                           int* __restrict__ col, float* __restrict__ wv, int E) {
    int e = blockIdx.x * blockDim.x + threadIdx.x;
    if (e < E) {
        int d = dst[e];
        int pos = atomicAdd(&fillhead[d], 1);
        col[pos] = src[e];
        wv[pos]  = ea[e];
    }
}

// ------------- single-plane aggregation, NPW nodes per wave -------------
// MODE 0: D = agg(S) (bf16). MODE 1: D = agg(S) + R (bf16). MODE 2: Df = agg(S) + R (f32).
// Edge loop unrolled x4 (4 independent gathers in flight).
template<int NC, int NPW, int MODE>
__global__ __launch_bounds__(256) void aggregate_sp(
    const u16* __restrict__ S, int SS,
    const int* __restrict__ rowptr, const int* __restrict__ col,
    const float* __restrict__ wv,
    const u16* __restrict__ R,
    u16* __restrict__ D, float* __restrict__ Df, int FD, int N)
{
    int wav  = (int)((blockIdx.x * 256 + threadIdx.x) >> 6);
    int lane = threadIdx.x & 63;
    int sub  = lane / NC;
    int cl   = lane % NC;
    int wid  = wav * NPW + sub;
    if (sub >= NPW || wid >= N) return;
    float acc0[8] = {}, acc1[8] = {}, acc2[8] = {}, acc3[8] = {};
    int beg = rowptr[wid], end = rowptr[wid + 1];
    int e = beg;
    for (; e + 4 <= end; e += 4) {
        float w0 = wv[e], w1 = wv[e + 1], w2 = wv[e + 2], w3 = wv[e + 3];
        int   c0 = col[e], c1 = col[e + 1], c2 = col[e + 2], c3 = col[e + 3];
        ushort8v v0 = *(const ushort8v*)&S[(size_t)c0 * SS + (cl << 3)];
        ushort8v v1 = *(const ushort8v*)&S[(size_t)c1 * SS + (cl << 3)];
        ushort8v v2 = *(const ushort8v*)&S[(size_t)c2 * SS + (cl << 3)];
        ushort8v v3 = *(const ushort8v*)&S[(size_t)c3 * SS + (cl << 3)];
#pragma unroll
        for (int r = 0; r < 8; ++r) {
            acc0[r] = fmaf(w0, bf16tof(v0[r]), acc0[r]);
            acc1[r] = fmaf(w1, bf16tof(v1[r]), acc1[r]);
            acc2[r] = fmaf(w2, bf16tof(v2[r]), acc2[r]);
            acc3[r] = fmaf(w3, bf16tof(v3[r]), acc3[r]);
        }
    }
    for (; e < end; ++e) {
        float w0 = wv[e];
        ushort8v v0 = *(const ushort8v*)&S[(size_t)col[e] * SS + (cl << 3)];
#pragma unroll
        for (int r = 0; r < 8; ++r) acc0[r] = fmaf(w0, bf16tof(v0[r]), acc0[r]);
    }
#pragma unroll
    for (int r = 0; r < 8; ++r) acc0[r] += (acc1[r] + acc2[r]) + acc3[r];
    if (MODE >= 1) {
        ushort8v v = *(const ushort8v*)&R[(size_t)wid * SS + (cl << 3)];
#pragma unroll
        for (int r = 0; r < 8; ++r) acc0[r] += bf16tof(v[r]);
    }
    if (MODE == 2) {
        float* o = &Df[(size_t)wid * FD + (cl << 3)];
        *(float4*)o       = make_float4(acc0[0], acc0[1], acc0[2], acc0[3]);
        *(float4*)(o + 4) = make_float4(acc0[4], acc0[5], acc0[6], acc0[7]);
    } else {
        ushort8v o;
#pragma unroll
        for (int r = 0; r < 8; ++r) o[r] = bf16rn(acc0[r]);
        *(ushort8v*)&D[(size_t)wid * FD + (cl << 3)] = o;
    }
}

// ------- gemm8: A bf16, B bf16, 128x256 tile, 4 waves of 64x128 -------
// C = A*B^T (+bias). DUALK=true: A=[A1|A2], B=[B1|B2] along K (KK=2*K1).
// DUALK=false: A=A1 (KK=K1); B rows r<NR1 -> B1[r] else B2[r-NR1] (col0 multiple
// of 256, NR1 % 256 == 0 -> uniform per block).
// LDS = 3 x 24KB buffers (A[128x32] | B[256x32]), 3-deep counted-vmcnt pipeline
// (identical accounting to gemm7: NCH=6 loads/thread/tile). 12 ds_read_b128 ->
// 32 MFMA per thread per step (arith intensity 43 FLOP/LDS-byte vs 32 before).
// Epilogue: acc -> LDS [128][264] -> 512B-row coalesced ushort8 stores.
template<bool DUALK>
__global__ __launch_bounds__(256) void gemm8(
    const u16* __restrict__ A1, const u16* __restrict__ A2,
    const u16* __restrict__ B1, const u16* __restrict__ B2,
    const float* __restrict__ biasA, const float* __restrict__ biasB,
    u16* __restrict__ Ch,
    int M, int K1, int NR1, int ldc, int doRelu)
{
    constexpr int NCH = 6;                 // staged 16B chunks per thread per tile
    constexpr int BUF = 12288;             // u16 per buffer: A 4096 + B 8192
    __shared__ u16 lds[3 * BUF];           // 72 KB

    const int tid = threadIdx.x;
    const int l = tid & 63, w = tid >> 6;
    const int wm = w >> 1, wn = w & 1;     // wave tile 64 rows x 128 cols
    const int lane15 = l & 15, slot = l >> 4;

    // ---- bijective XCD-chunk swizzle (m204) ----
    const int nwg = gridDim.x * gridDim.y;
    const int bid = blockIdx.y * gridDim.x + blockIdx.x;
    const int q = nwg >> 3, r8 = nwg & 7;
    const int xcd = bid & 7, v = bid >> 3;
    const int sw = (xcd < r8) ? xcd * (q + 1) + v : r8 * (q + 1) + (xcd - r8) * q + v;
    const int row0 = (sw / gridDim.x) * 128;
    const int col0 = (sw % gridDim.x) * 256;

    const int KK = DUALK ? 2 * K1 : K1;
    const int nsteps = KK / 32;

    // ---- staging precompute: 1536 chunks (A 512 + B 1024), 6 per thread ----
    const u16* q1[NCH]; const u16* q2[NCH]; int lim[NCH]; int dstoff[NCH];
#pragma unroll
    for (int i = 0; i < NCH; ++i) {
        int c = i * 256 + tid;              // global chunk 0..1535 (plane-uniform per i)
        bool isA = (c < 512);
        int cp = isA ? c : (c - 512);
        int rw = cp >> 2, ch = cp & 3;
        int cpk = (ch ^ ((rw >> 1) & 3)) << 3;  // swizzled source k-offset (u16)
        lim[i]    = K1 - cpk;
        dstoff[i] = (isA ? 0 : 4096) + (cp << 3);
        const u16 *b1, *b2; int g;
        if (isA) {
            b1 = A1; b2 = A2 - K1;
            g = min(row0 + rw, M - 1);
        } else {
            if (DUALK) { b1 = B1; b2 = B2 - K1; g = col0 + rw; }
            else {
                bool sec = (col0 >= NR1);
                b1 = sec ? B2 : B1; b2 = b1;
                g = col0 + rw - (sec ? NR1 : 0);
            }
        }
        q1[i] = b1 + g * K1 + cpk;
        q2[i] = b2 + g * K1 + cpk;
    }

    auto stage = [&](u16* base, int kk0) {
#pragma unroll
        for (int i = 0; i < NCH; ++i) {
            const u16* s = (DUALK && kk0 >= lim[i]) ? q2[i] : q1[i];
            gload_lds16(s + kk0, base + dstoff[i]);
        }
    };

    f32x4 acc[4][8] = {};

    // ---- prologue: stage tiles 0 and 1 ----
    stage(lds, 0);
    if (nsteps > 1) {
        stage(lds + BUF, 32);
        asm volatile("s_waitcnt vmcnt(%0)" :: "n"(NCH) : "memory");  // tile0 landed
    } else {
        asm volatile("s_waitcnt vmcnt(0)" ::: "memory");
    }
    __builtin_amdgcn_s_barrier();
    __builtin_amdgcn_sched_barrier(0);

    int ro = 0, so = 2 * BUF;
    for (int step = 0; step < nsteps; ++step) {
        const u16* cb = lds + ro;
        // ---- 1. ds_read fragments of current tile ----
        short8v av[4], bh[8];
#pragma unroll
        for (int bi = 0; bi < 4; ++bi) {
            int r = wm * 64 + bi * 16 + lane15;
            int j = slot ^ ((r >> 1) & 3);
            av[bi] = *(const short8v*)&cb[r * 32 + j * 8];
        }
#pragma unroll
        for (int bj = 0; bj < 8; ++bj) {
            int c = wn * 128 + bj * 16 + lane15;
            int j = slot ^ ((c >> 1) & 3);
            bh[bj] = *(const short8v*)&cb[4096 + c * 32 + j * 8];
        }
        // ---- 2. issue stage of tile t+2 (stays in flight across the barrier) ----
        if (step + 2 < nsteps) stage(lds + so, (step + 2) * 32);
        // ---- 3. MFMA ----
#pragma unroll
        for (int bj = 0; bj < 8; ++bj)
#pragma unroll
            for (int bi = 0; bi < 4; ++bi)
                acc[bi][bj] = __builtin_amdgcn_mfma_f32_16x16x32_bf16(av[bi], bh[bj], acc[bi][bj], 0, 0, 0);
        // ---- 4. counted wait: only tile t+1's loads must land ----
        if (step + 1 < nsteps) {
            if (step + 2 < nsteps)
                asm volatile("s_waitcnt vmcnt(%0)" :: "n"(NCH) : "memory");
            else
                asm volatile("s_waitcnt vmcnt(0)" ::: "memory");
            __builtin_amdgcn_s_barrier();
            __builtin_amdgcn_sched_barrier(0);
        }
        ro += BUF; if (ro == 3 * BUF) ro = 0;
        so += BUF; if (so == 3 * BUF) so = 0;
    }

    // ---- epilogue: acc -> LDS tile [128][264] -> coalesced 512B-row stores ----
    __syncthreads();
    u16* ct = lds;                  // 128 x 264 u16 = 67584 B (fits 73728)
#pragma unroll
    for (int bj = 0; bj < 8; ++bj) {
        int cc = wn * 128 + bj * 16 + lane15;
        int gc = col0 + cc;
        float bv = (gc < NR1) ? (biasA ? biasA[gc] : 0.f)
                              : (biasB ? biasB[gc - NR1] : 0.f);
#pragma unroll
        for (int bi = 0; bi < 4; ++bi) {
            int rb = wm * 64 + bi * 16 + slot * 4;
#pragma unroll
            for (int qq = 0; qq < 4; ++qq) {
                float o = acc[bi][bj][qq] + bv;
                if (doRelu) o = fmaxf(o, 0.f);
                ct[(rb + qq) * 264 + cc] = bf16rn(o);
            }
        }
    }
    __syncthreads();
#pragma unroll
    for (int it = 0; it < 16; ++it) {
        int row = it * 8 + (tid >> 5);
        int c16 = (tid & 31) * 8;
        int gr = row0 + row;
        if (gr < M) {
            ushort8v vv = *(const ushort8v*)&ct[row * 264 + c16];
            *(ushort8v*)&Ch[(size_t)gr * ldc + col0 + c16] = vv;
        }
    }
}

// ------- gemm7 (kept for L4): A bf16, B fp24 hi/lo, 128x128, 2-term -------
#define GBM 128
#define GBN 128

template<bool DUALK, int BT>
__global__ __launch_bounds__(256) void gemm7(
    const u16* __restrict__ A1, const u16* __restrict__ A2,
    const u16* __restrict__ B1h, const u16* __restrict__ B1l,
    const u16* __restrict__ B2h, const u16* __restrict__ B2l,
    const float* __restrict__ biasA, const float* __restrict__ biasB,
    u16* __restrict__ Ch,
    int M, int K1, int NR1, int ldc, int doRelu)
{
    constexpr int NP  = 1 + BT;
    constexpr int NCH = 2 * NP;
    constexpr int BUF = NP * 4096;
    __shared__ u16 lds[3 * BUF];

    const int tid = threadIdx.x;
    const int l = tid & 63, w = tid >> 6;
    const int wm = w >> 1, wn = w & 1;
    const int lane15 = l & 15, slot = l >> 4;

    const int nwg = gridDim.x * gridDim.y;
    const int bid = blockIdx.y * gridDim.x + blockIdx.x;
    const int q = nwg >> 3, r8 = nwg & 7;
    const int xcd = bid & 7, v = bid >> 3;
    const int sw = (xcd < r8) ? xcd * (q + 1) + v : r8 * (q + 1) + (xcd - r8) * q + v;
    const int row0 = (sw / gridDim.x) * GBM;
    const int col0 = (sw % gridDim.x) * GBN;

    const int KK = DUALK ? 2 * K1 : K1;
    const int nsteps = KK / 32;

    const u16* q1[NCH]; const u16* q2[NCH]; int lim[NCH]; int dstoff[NCH];
#pragma unroll
    for (int i = 0; i < NCH; ++i) {
        int idx0  = i * 256 + (tid & ~63);
        int p     = idx0 >> 9;
        int cbase = idx0 & 511;
        int c  = cbase + l;
        int rw = c >> 2, ch = c & 3;
        int cpk = (ch ^ ((rw >> 1) & 3)) << 3;
        lim[i]    = K1 - cpk;
        dstoff[i] = (p << 12) + (cbase << 3);
        const u16 *b1, *b2; int g;
        if (p == 0) {
            b1 = A1; b2 = A2 - K1;
            g = min(row0 + rw, M - 1);
        } else {
            const u16* h1 = (p == 1) ? B1h : B1l;
            const u16* h2 = (p == 1) ? B2h : B2l;
            if (DUALK) { b1 = h1; b2 = h2 - K1; g = col0 + rw; }
            else {
                bool sec = (col0 >= NR1);
                b1 = sec ? h2 : h1; b2 = b1;
                g = col0 + rw - (sec ? NR1 : 0);
            }
        }
        q1[i] = b1 + g * K1 + cpk;
        q2[i] = b2 + g * K1 + cpk;
    }

    auto stage = [&](u16* base, int kk0) {
#pragma unroll
        for (int i = 0; i < NCH; ++i) {
            const u16* s = (DUALK && kk0 >= lim[i]) ? q2[i] : q1[i];
            gload_lds16(s + kk0, base + dstoff[i]);
        }
    };

    f32x4 acc[4][4] = {};

    stage(lds, 0);
    if (nsteps > 1) {
        stage(lds + BUF, 32);
        asm volatile("s_waitcnt vmcnt(%0)" :: "n"(NCH) : "memory");
    } else {
        asm volatile("s_waitcnt vmcnt(0)" ::: "memory");
    }
    __builtin_amdgcn_s_barrier();
    __builtin_amdgcn_sched_barrier(0);

    int ro = 0, so = 2 * BUF;
    for (int step = 0; step < nsteps; ++step) {
        const u16* cb = lds + ro;
        short8v av[4], bh[4], bl[4];
#pragma unroll
        for (int bi = 0; bi < 4; ++bi) {
            int r = wm * 64 + bi * 16 + lane15;
            int j = slot ^ ((r >> 1) & 3);
            av[bi] = *(const short8v*)&cb[r * 32 + j * 8];
        }
#pragma unroll
        for (int bj = 0; bj < 4; ++bj) {
            int c = wn * 64 + bj * 16 + lane15;
            int j = slot ^ ((c >> 1) & 3);
            bh[bj] = *(const short8v*)&cb[4096 + c * 32 + j * 8];
            if (BT == 2) bl[bj] = *(const short8v*)&cb[8192 + c * 32 + j * 8];
        }
        if (step + 2 < nsteps) stage(lds + so, (step + 2) * 32);
#pragma unroll
        for (int bj = 0; bj < 4; ++bj)
#pragma unroll
            for (int bi = 0; bi < 4; ++bi) {
                acc[bi][bj] = __builtin_amdgcn_mfma_f32_16x16x32_bf16(av[bi], bh[bj], acc[bi][bj], 0, 0, 0);
                if (BT == 2)
                    acc[bi][bj] = __builtin_amdgcn_mfma_f32_16x16x32_bf16(av[bi], bl[bj], acc[bi][bj], 0, 0, 0);
            }
        if (step + 1 < nsteps) {
            if (step + 2 < nsteps)
                asm volatile("s_waitcnt vmcnt(%0)" :: "n"(NCH) : "memory");
            else
                asm volatile("s_waitcnt vmcnt(0)" ::: "memory");
            __builtin_amdgcn_s_barrier();
            __builtin_amdgcn_sched_barrier(0);
        }
        ro += BUF; if (ro == 3 * BUF) ro = 0;
        so += BUF; if (so == 3 * BUF) so = 0;
    }

    __syncthreads();
    u16* ct = lds;                 // 128 x 132 u16
#pragma unroll
    for (int bj = 0; bj < 4; ++bj) {
        int cc = wn * 64 + bj * 16 + lane15;
        int gc = col0 + cc;
        float bv = (gc < NR1) ? (biasA ? biasA[gc] : 0.f)
                              : (biasB ? biasB[gc - NR1] : 0.f);
#pragma unroll
        for (int bi = 0; bi < 4; ++bi) {
            int rb = wm * 64 + bi * 16 + slot * 4;
#pragma unroll
            for (int qq = 0; qq < 4; ++qq) {
                float o = acc[bi][bj][qq] + bv;
                if (doRelu) o = fmaxf(o, 0.f);
                ct[(rb + qq) * 132 + cc] = bf16rn(o);
            }
        }
    }
    __syncthreads();
#pragma unroll
    for (int it = 0; it < 8; ++it) {
        int row = it * 16 + (tid >> 4);
        int c16 = (tid & 15) * 8;
        int gr = row0 + row;
        if (gr < M) {
            ushort8v vv = *(const ushort8v*)&ct[row * 132 + c16];
            *(ushort8v*)&Ch[(size_t)gr * ldc + col0 + c16] = vv;
        }
    }
}

// ---------------- GraphNorm stats (F = 256): 8 row-streams x 32 chunks / block ----
__global__ __launch_bounds__(256) void colstats2(const u16* __restrict__ H,
                                                 float* __restrict__ sums,
                                                 float* __restrict__ sqs, int N) {
    __shared__ float lsum[8][256];
    __shared__ float lsq[8][256];
    int t  = threadIdx.x;
    int g  = t >> 5;
    int cl = t & 31;
    float s[8] = {}, q[8] = {};
    for (int row = blockIdx.x * 8 + g; row < N; row += gridDim.x * 8) {
        ushort8v v = *(const ushort8v*)&H[(size_t)row * 256 + (cl << 3)];
#pragma unroll
        for (int r = 0; r < 8; ++r) {
            float f = bf16tof(v[r]);
            s[r] += f;
            q[r] = fmaf(f, f, q[r]);
        }
    }
#pragma unroll
    for (int r = 0; r < 8; ++r) {
        lsum[g][(cl << 3) + r] = s[r];
        lsq[g][(cl << 3) + r]  = q[r];
    }
    __syncthreads();
    float ts = 0.f, tq = 0.f;
#pragma unroll
    for (int gg = 0; gg < 8; ++gg) { ts += lsum[gg][t]; tq += lsq[gg][t]; }
    atomicAdd(&sums[t], ts);
    atomicAdd(&sqs[t], tq);
}

__global__ void norm_prep(const float* __restrict__ sums, const float* __restrict__ sqs,
                          const float* __restrict__ gw, const float* __restrict__ gb,
                          const float* __restrict__ gms, float* __restrict__ scaleF,
                          float* __restrict__ shiftF, float invN) {
    int f = threadIdx.x;
    float mu  = sums[f] * invN;
    float ex2 = sqs[f] * invN;
    float a   = gms[f] * mu;
    float var = ex2 - 2.f * a * mu + a * a;
    float inv = rsqrtf(var + 1e-5f);
    float sc  = gw[f] * inv;
    scaleF[f] = sc;
    shiftF[f] = gb[f] - a * sc;
}

__global__ __launch_bounds__(256) void norm_apply_sp(
    u16* __restrict__ H, const float* __restrict__ scaleF,
    const float* __restrict__ shiftF, int n8) {
    int i = blockIdx.x * 256 + threadIdx.x;
    if (i >= n8) return;
    int f0 = (i & 31) << 3;
    ushort8v h = *(const ushort8v*)&H[(size_t)i * 8];
    ushort8v o;
#pragma unroll
    for (int r = 0; r < 8; ++r) {
        float v = fmaxf(fmaf(bf16tof(h[r]), scaleF[f0 + r], shiftF[f0 + r]), 0.f);
        o[r] = bf16rn(v);
    }
    *(ushort8v*)&H[(size_t)i * 8] = o;
}

// ---------------- launch ----------------
extern "C" void kernel_launch(void* const* d_in, const int* in_sizes, int n_in,
                              void* d_out, int out_size, void* d_ws, size_t ws_size,
                              hipStream_t stream) {
    const float* x   = (const float*)d_in[0];
    const int*   ei  = (const int*)d_in[1];
    const float* ea  = (const float*)d_in[2];
    const float* Wr1 = (const float*)d_in[3];
    const float* b1  = (const float*)d_in[4];
    const float* Wo1 = (const float*)d_in[5];
    const float* Wr2 = (const float*)d_in[6];
    const float* b2  = (const float*)d_in[7];
    const float* Wo2 = (const float*)d_in[8];
    const float* Wr3 = (const float*)d_in[9];
    const float* b3  = (const float*)d_in[10];
    const float* Wo3 = (const float*)d_in[11];
    const float* Wr4 = (const float*)d_in[12];
    const float* b4  = (const float*)d_in[13];
    const float* Wo4 = (const float*)d_in[14];
    const float* gw  = (const float*)d_in[15];
    const float* gb  = (const float*)d_in[16];
    const float* gms = (const float*)d_in[17];

    const int Nn = in_sizes[0] / F_IN;   // 50000
    const int E  = in_sizes[1] / 2;      // 400000
    const int* src = ei;
    const int* dst = ei + E;

    char* wp = (char*)d_ws;
    auto alloc = [&](size_t bytes) -> void* {
        void* p = (void*)wp;
        wp += (bytes + 255) & ~(size_t)255;
        return p;
    };
    int*   counts   = (int*)alloc((size_t)Nn * 4);
    int*   rowptr   = (int*)alloc((size_t)(Nn + 1) * 4);
    int*   fillhead = (int*)alloc((size_t)Nn * 4);
    int*   col      = (int*)alloc((size_t)E * 4);
    float* wv       = (float*)alloc((size_t)E * 4);
    float* stats    = (float*)alloc(1024 * 4);
    float* sums = stats, *sqs = stats + 256, *scaleF = stats + 512, *shiftF = stats + 768;
    int*   bsum     = (int*)alloc(256 * 4);
    int*   boff     = (int*)alloc(256 * 4);
    // weights: L1-L3 single bf16 plane, L4 fp24 hi/lo
    u16* wr1 = (u16*)alloc(2u * 256 * 144);
    u16* wo1 = (u16*)alloc(2u * 256 * 144);
    u16* wr2 = (u16*)alloc(2u * 512 * 256);
    u16* wo2 = (u16*)alloc(2u * 512 * 256);
    u16* wr3 = (u16*)alloc(2u * 256 * 512);
    u16* wo3 = (u16*)alloc(2u * 256 * 512);
    u16* wr4h = (u16*)alloc(2u * 128 * 256); u16* wr4l = (u16*)alloc(2u * 128 * 256);
    u16* wo4h = (u16*)alloc(2u * 128 * 256); u16* wo4l = (u16*)alloc(2u * 128 * 256);

    // ---- lifetime-packed region (u16 units), Nn*1168*2 B = 116.8 MB ----
    u16* big = (u16*)alloc((size_t)Nn * 1168 * 2);
    const size_t NS = (size_t)Nn;
    u16* Xb  = big;
    u16* AG  = big + NS * 144;
    u16* H1  = big + NS * 400;
    u16* H2  = big + NS * 656;
    u16* Y3  = big;
    u16* H3  = big + NS * 656;
    u16* Y4  = big;

    const int TB = 256;
    // CSR build (parallel scan)
    int nbScan = (Nn + SCB - 1) / SCB;
    zero_i32<<<(Nn + TB - 1) / TB, TB, 0, stream>>>(counts, Nn);
    count_edges<<<(E + TB - 1) / TB, TB, 0, stream>>>(dst, counts, E);
    scan_partial<<<nbScan, TB, 0, stream>>>(counts, rowptr, bsum, Nn);
    scan_tops<<<1, TB, 0, stream>>>(bsum, boff, nbScan);
    scan_add<<<(Nn + 1 + TB - 1) / TB, TB, 0, stream>>>(rowptr, fillhead, boff, Nn, E);
    fill_edges<<<(E + TB - 1) / TB, TB, 0, stream>>>(src, dst, ea, fillhead, col, wv, E);

    // conversions
    int nx = Nn * F_IN;
    conv_bf<<<(nx + 255) / 256, 256, 0, stream>>>(x, Xb, nx);
    struct BC { const float* s; u16* d; int n; } bc[6] = {
        {Wr1, wr1, 256 * 144}, {Wo1, wo1, 256 * 144},
        {Wr2, wr2, 512 * 256}, {Wo2, wo2, 512 * 256},
        {Wr3, wr3, 256 * 512}, {Wo3, wo3, 256 * 512}};
    for (int i = 0; i < 6; ++i)
        conv_bf<<<(bc[i].n + 255) / 256, 256, 0, stream>>>(bc[i].s, bc[i].d, bc[i].n);
    conv_hl<<<(128 * 256 + 255) / 256, 256, 0, stream>>>(Wr4, wr4h, wr4l, 128 * 256);
    conv_hl<<<(128 * 256 + 255) / 256, 256, 0, stream>>>(Wo4, wo4h, wo4l, 128 * 256);

    int mB = (Nn + 127) / 128;                  // 391
    int g3 = (((Nn + 2) / 3) + 3) / 4;
    int g2 = (((Nn + 1) / 2) + 3) / 4;
    int g4 = (((Nn + 3) / 4) + 3) / 4;

    // Layer 1 (aggregate-first): AG = agg(X); H1 = relu([AG|X]*[Wr1|Wo1]^T + b1)
    aggregate_sp<18, 3, 0><<<g3, TB, 0, stream>>>(Xb, 144, rowptr, col, wv,
                                                  nullptr, AG, nullptr, 144, Nn);
    gemm8<true><<<dim3(1, mB), 256, 0, stream>>>(AG, Xb, wr1, wo1,
                                                 b1, nullptr, H1,
                                                 Nn, 144, 256, 256, 1);
    // Layer 2 (aggregate-first): AG = agg(H1); H2 = relu([AG|H1]*[Wr2|Wo2]^T + b2)
    aggregate_sp<32, 2, 0><<<g2, TB, 0, stream>>>(H1, 256, rowptr, col, wv,
                                                  nullptr, AG, nullptr, 256, Nn);
    gemm8<true><<<dim3(2, mB), 256, 0, stream>>>(AG, H1, wr2, wo2,
                                                 b2, nullptr, H2,
                                                 Nn, 256, 512, 512, 1);
    // Layer 3 (transform-first): Y3 = [H2*Wr3^T | H2*Wo3^T + b3]; H3 = agg(Yrel)+Yroot
    gemm8<false><<<dim3(2, mB), 256, 0, stream>>>(H2, H2, wr3, wo3,
                                                  nullptr, b3, Y3,
                                                  Nn, 512, 256, 512, 0);
    aggregate_sp<32, 2, 1><<<g2, TB, 0, stream>>>(Y3, 512, rowptr, col, wv,
                                                  Y3 + 256, H3, nullptr, 256, Nn);
    // GraphNorm + relu in place on H3
    zero_f32<<<2, TB, 0, stream>>>(stats, 512);
    colstats2<<<800, TB, 0, stream>>>(H3, sums, sqs, Nn);
    norm_prep<<<1, 256, 0, stream>>>(sums, sqs, gw, gb, gms, scaleF, shiftF, 1.0f / Nn);
    norm_apply_sp<<<(Nn * 32 + TB - 1) / TB, TB, 0, stream>>>(H3, scaleF, shiftF, Nn * 32);
    // Layer 4 (transform-first, fp24 weights): Y4 = [H3*Wr4^T | H3*Wo4^T + b4] (bf16);
    // out = agg(Y4rel) + Y4root (f32)
    gemm7<false, 2><<<dim3(2, mB), 256, 0, stream>>>(H3, H3, wr4h, wr4l, wo4h, wo4l,
                                                     nullptr, b4, Y4,
                                                     Nn, 256, 128, 256, 0);
    aggregate_sp<16, 4, 2><<<g4, TB, 0, stream>>>(Y4, 256, rowptr, col, wv,
                                                  Y4 + 128, nullptr, (float*)d_out, 128, Nn);
}

// Round 16
// 377.520 us; speedup vs baseline: 1.1262x; 1.1262x over previous
//
#include <hip/hip_runtime.h>

#define F_IN 144
typedef __attribute__((ext_vector_type(8))) short short8v;
typedef __attribute__((ext_vector_type(8))) unsigned short ushort8v;
typedef __attribute__((ext_vector_type(4))) float f32x4;
typedef unsigned short u16;

// ---------------- bf16 helpers ----------------
__device__ __forceinline__ u16 bf16rn(float x) {
    union { float f; unsigned u; } a; a.f = x;
    return (u16)((a.u + 0x7FFFu + ((a.u >> 16) & 1u)) >> 16);
}
__device__ __forceinline__ float bf16tof(u16 h) {
    union { float f; unsigned u; } a; a.u = ((unsigned)h) << 16;
    return a.f;
}
__device__ __forceinline__ void gload_lds16(const u16* g, u16* s) {
    __builtin_amdgcn_global_load_lds(
        (const __attribute__((address_space(1))) void*)g,
        (__attribute__((address_space(3))) void*)s, 16, 0, 0);
}

// ---------------- utility ----------------
__global__ void zero_i32(int* __restrict__ p, int n) {
    int i = blockIdx.x * blockDim.x + threadIdx.x;
    if (i < n) p[i] = 0;
}
__global__ void zero_f32(float* __restrict__ p, int n) {
    int i = blockIdx.x * blockDim.x + threadIdx.x;
    if (i < n) p[i] = 0.f;
}
// weights: f32 -> bf16 hi/lo (fp24)
__global__ void conv_hl(const float* __restrict__ src, u16* __restrict__ dh,
                        u16* __restrict__ dl, int n) {
    int i = blockIdx.x * 256 + threadIdx.x;
    if (i < n) {
        float v = src[i];
        u16 h = bf16rn(v);
        dh[i] = h;
        dl[i] = bf16rn(v - bf16tof(h));
    }
}
// f32 -> bf16 single plane
__global__ void conv_bf(const float* __restrict__ src, u16* __restrict__ d, int n) {
    int i = blockIdx.x * 256 + threadIdx.x;
    if (i < n) d[i] = bf16rn(src[i]);
}

// ---------------- CSR build ----------------
__global__ void count_edges(const int* __restrict__ dst, int* __restrict__ counts, int E) {
    int e = blockIdx.x * blockDim.x + threadIdx.x;
    if (e < E) atomicAdd(&counts[dst[e]], 1);
}

// 3-pass parallel exclusive scan (2048 elements per block)
#define SCB 2048
__global__ __launch_bounds__(256) void scan_partial(const int* __restrict__ counts,
                                                    int* __restrict__ rowptr,
                                                    int* __restrict__ bsum, int N) {
    __shared__ int ls[256];
    int t = threadIdx.x;
    int base = blockIdx.x * SCB + t * 8;
    int v[8]; int s = 0;
#pragma unroll
    for (int j = 0; j < 8; ++j) {
        int i = base + j;
        v[j] = (i < N) ? counts[i] : 0;
        s += v[j];
    }
    ls[t] = s;
    __syncthreads();
    for (int off = 1; off < 256; off <<= 1) {
        int x = (t >= off) ? ls[t - off] : 0;
        __syncthreads();
        ls[t] += x;
        __syncthreads();
    }
    int run = (t == 0) ? 0 : ls[t - 1];
#pragma unroll
    for (int j = 0; j < 8; ++j) {
        int i = base + j;
        if (i < N) rowptr[i] = run;
        run += v[j];
    }
    if (t == 255) bsum[blockIdx.x] = ls[255];
}

__global__ __launch_bounds__(256) void scan_tops(const int* __restrict__ bsum,
                                                 int* __restrict__ boff, int nb) {
    __shared__ int ls[256];
    int t = threadIdx.x;
    ls[t] = (t < nb) ? bsum[t] : 0;
    __syncthreads();
    for (int off = 1; off < 256; off <<= 1) {
        int x = (t >= off) ? ls[t - off] : 0;
        __syncthreads();
        ls[t] += x;
        __syncthreads();
    }
    boff[t] = (t == 0) ? 0 : ls[t - 1];   // exclusive block prefix
}

__global__ void scan_add(int* __restrict__ rowptr, int* __restrict__ fillhead,
                         const int* __restrict__ boff, int N, int E) {
    int i = blockIdx.x * 256 + threadIdx.x;
    if (i < N) {
        int r = rowptr[i] + boff[i >> 11];   // SCB = 2048 = 1<<11
        rowptr[i] = r;
        fillhead[i] = r;
    }
    if (i == N) rowptr[N] = E;
}

__global__ void fill_edges(const int* __restrict__ src, const int* __restrict__ dst,
                           const float* __restrict__ ea, int* __restrict__ fillhead,
                           int* __restrict__ col, float* __restrict__ wv, int E) {
    int e = blockIdx.x * blockDim.x + threadIdx.x;
    if (e < E) {
        int d = dst[e];
        int pos = atomicAdd(&fillhead[d], 1);
        col[pos] = src[e];
        wv[pos]  = ea[e];
    }
}

// ------------- single-plane aggregation, NPW nodes per wave -------------
// MODE 0: D = agg(S) (bf16). MODE 1: D = agg(S) + R (bf16). MODE 2: Df = agg(S) + R (f32).
// Edge loop unrolled x4 (4 independent gathers in flight).
template<int NC, int NPW, int MODE>
__global__ __launch_bounds__(256) void aggregate_sp(
    const u16* __restrict__ S, int SS,
    const int* __restrict__ rowptr, const int* __restrict__ col,
    const float* __restrict__ wv,
    const u16* __restrict__ R,
    u16* __restrict__ D, float* __restrict__ Df, int FD, int N)
{
    int wav  = (int)((blockIdx.x * 256 + threadIdx.x) >> 6);
    int lane = threadIdx.x & 63;
    int sub  = lane / NC;
    int cl   = lane % NC;
    int wid  = wav * NPW + sub;
    if (sub >= NPW || wid >= N) return;
    float acc0[8] = {}, acc1[8] = {}, acc2[8] = {}, acc3[8] = {};
    int beg = rowptr[wid], end = rowptr[wid + 1];
    int e = beg;
    for (; e + 4 <= end; e += 4) {
        float w0 = wv[e], w1 = wv[e + 1], w2 = wv[e + 2], w3 = wv[e + 3];
        int   c0 = col[e], c1 = col[e + 1], c2 = col[e + 2], c3 = col[e + 3];
        ushort8v v0 = *(const ushort8v*)&S[(size_t)c0 * SS + (cl << 3)];
        ushort8v v1 = *(const ushort8v*)&S[(size_t)c1 * SS + (cl << 3)];
        ushort8v v2 = *(const ushort8v*)&S[(size_t)c2 * SS + (cl << 3)];
        ushort8v v3 = *(const ushort8v*)&S[(size_t)c3 * SS + (cl << 3)];
#pragma unroll
        for (int r = 0; r < 8; ++r) {
            acc0[r] = fmaf(w0, bf16tof(v0[r]), acc0[r]);
            acc1[r] = fmaf(w1, bf16tof(v1[r]), acc1[r]);
            acc2[r] = fmaf(w2, bf16tof(v2[r]), acc2[r]);
            acc3[r] = fmaf(w3, bf16tof(v3[r]), acc3[r]);
        }
    }
    for (; e < end; ++e) {
        float w0 = wv[e];
        ushort8v v0 = *(const ushort8v*)&S[(size_t)col[e] * SS + (cl << 3)];
#pragma unroll
        for (int r = 0; r < 8; ++r) acc0[r] = fmaf(w0, bf16tof(v0[r]), acc0[r]);
    }
#pragma unroll
    for (int r = 0; r < 8; ++r) acc0[r] += (acc1[r] + acc2[r]) + acc3[r];
    if (MODE >= 1) {
        ushort8v v = *(const ushort8v*)&R[(size_t)wid * SS + (cl << 3)];
#pragma unroll
        for (int r = 0; r < 8; ++r) acc0[r] += bf16tof(v[r]);
    }
    if (MODE == 2) {
        float* o = &Df[(size_t)wid * FD + (cl << 3)];
        *(float4*)o       = make_float4(acc0[0], acc0[1], acc0[2], acc0[3]);
        *(float4*)(o + 4) = make_float4(acc0[4], acc0[5], acc0[6], acc0[7]);
    } else {
        ushort8v o;
#pragma unroll
        for (int r = 0; r < 8; ++r) o[r] = bf16rn(acc0[r]);
        *(ushort8v*)&D[(size_t)wid * FD + (cl << 3)] = o;
    }
}

// ------- gemm7: A bf16, B = BT planes (1: bf16, 2: fp24 hi/lo) -------
// C = A*(sum of B planes)^T (+bias), bf16 out via LDS-coalesced epilogue.
// DUALK=true: A=[A1|A2], B=[B1|B2] along K (KK=2*K1).
// DUALK=false: A=A1 (KK=K1); B rows r<NR1 -> B1[r] else B2[r-NR1] (NR1 % 128 == 0).
// 128x128 tile, 4 waves. LDS = 3 x (1+BT)*8KB buffers, 3-deep pipeline:
// step t reads buf[t%3], issues stage of tile t+2 into buf[(t+2)%3], MFMAs
// (wrapped in s_setprio(1/0) — T5), then s_waitcnt vmcnt(NCH) + raw s_barrier +
// sched_barrier(0). Never vmcnt(0) in steady state (T3/T4). Bijective XCD-chunk
// swizzle (m204). Epilogue: acc -> LDS [128][132] -> 256B-row coalesced stores.
#define GBM 128
#define GBN 128

template<bool DUALK, int BT>
__global__ __launch_bounds__(256) void gemm7(
    const u16* __restrict__ A1, const u16* __restrict__ A2,
    const u16* __restrict__ B1h, const u16* __restrict__ B1l,
    const u16* __restrict__ B2h, const u16* __restrict__ B2l,
    const float* __restrict__ biasA, const float* __restrict__ biasB,
    u16* __restrict__ Ch,
    int M, int K1, int NR1, int ldc, int doRelu)
{
    constexpr int NP  = 1 + BT;           // LDS planes: A, Bh[, Bl]
    constexpr int NCH = 2 * NP;           // staged chunks (loads) per thread per tile
    constexpr int BUF = NP * 4096;        // u16 per buffer
    __shared__ u16 lds[3 * BUF];          // BT=1: 48KB, BT=2: 72KB

    const int tid = threadIdx.x;
    const int l = tid & 63, w = tid >> 6;
    const int wm = w >> 1, wn = w & 1;
    const int lane15 = l & 15, slot = l >> 4;

    // ---- bijective XCD-chunk swizzle (m204) ----
    const int nwg = gridDim.x * gridDim.y;
    const int bid = blockIdx.y * gridDim.x + blockIdx.x;
    const int q = nwg >> 3, r8 = nwg & 7;
    const int xcd = bid & 7, v = bid >> 3;
    const int sw = (xcd < r8) ? xcd * (q + 1) + v : r8 * (q + 1) + (xcd - r8) * q + v;
    const int row0 = (sw / gridDim.x) * GBM;
    const int col0 = (sw % gridDim.x) * GBN;

    const int KK = DUALK ? 2 * K1 : K1;
    const int nsteps = KK / 32;

    // ---- staging precompute: NP planes x 512 chunks, NCH per thread ----
    const u16* q1[NCH]; const u16* q2[NCH]; int lim[NCH]; int dstoff[NCH];
#pragma unroll
    for (int i = 0; i < NCH; ++i) {
        int idx0  = i * 256 + (tid & ~63);      // wave-uniform
        int p     = idx0 >> 9;                  // plane 0:A 1:Bh 2:Bl
        int cbase = idx0 & 511;
        int c  = cbase + l;                     // per-lane chunk
        int rw = c >> 2, ch = c & 3;
        int cpk = (ch ^ ((rw >> 1) & 3)) << 3;  // swizzled source k-offset (u16)
        lim[i]    = K1 - cpk;
        dstoff[i] = (p << 12) + (cbase << 3);
        const u16 *b1, *b2; int g;
        if (p == 0) {
            b1 = A1; b2 = A2 - K1;
            g = min(row0 + rw, M - 1);
        } else {
            const u16* h1 = (p == 1) ? B1h : B1l;
            const u16* h2 = (p == 1) ? B2h : B2l;
            if (DUALK) { b1 = h1; b2 = h2 - K1; g = col0 + rw; }
            else {
                bool sec = (col0 >= NR1);
                b1 = sec ? h2 : h1; b2 = b1;
                g = col0 + rw - (sec ? NR1 : 0);
            }
        }
        q1[i] = b1 + g * K1 + cpk;
        q2[i] = b2 + g * K1 + cpk;
    }

    auto stage = [&](u16* base, int kk0) {
#pragma unroll
        for (int i = 0; i < NCH; ++i) {
            const u16* s = (DUALK && kk0 >= lim[i]) ? q2[i] : q1[i];
            gload_lds16(s + kk0, base + dstoff[i]);
        }
    };

    f32x4 acc[4][4] = {};

    // ---- prologue: stage tiles 0 and 1 ----
    stage(lds, 0);
    if (nsteps > 1) {
        stage(lds + BUF, 32);
        asm volatile("s_waitcnt vmcnt(%0)" :: "n"(NCH) : "memory");  // tile0 landed
    } else {
        asm volatile("s_waitcnt vmcnt(0)" ::: "memory");
    }
    __builtin_amdgcn_s_barrier();
    __builtin_amdgcn_sched_barrier(0);

    int ro = 0, so = 2 * BUF;   // read offset (t%3), stage offset ((t+2)%3)
    for (int step = 0; step < nsteps; ++step) {
        const u16* cb = lds + ro;
        // ---- 1. ds_read fragments of current tile ----
        short8v av[4], bh[4], bl[4];
#pragma unroll
        for (int bi = 0; bi < 4; ++bi) {
            int r = wm * 64 + bi * 16 + lane15;
            int j = slot ^ ((r >> 1) & 3);
            av[bi] = *(const short8v*)&cb[r * 32 + j * 8];
        }
#pragma unroll
        for (int bj = 0; bj < 4; ++bj) {
            int c = wn * 64 + bj * 16 + lane15;
            int j = slot ^ ((c >> 1) & 3);
            bh[bj] = *(const short8v*)&cb[4096 + c * 32 + j * 8];
            if (BT == 2) bl[bj] = *(const short8v*)&cb[8192 + c * 32 + j * 8];
        }
        // ---- 2. issue stage of tile t+2 (stays in flight across the barrier) ----
        if (step + 2 < nsteps) stage(lds + so, (step + 2) * 32);
        // ---- 3. MFMA (T5: setprio around the matrix cluster) ----
        __builtin_amdgcn_s_setprio(1);
#pragma unroll
        for (int bj = 0; bj < 4; ++bj)
#pragma unroll
            for (int bi = 0; bi < 4; ++bi) {
                acc[bi][bj] = __builtin_amdgcn_mfma_f32_16x16x32_bf16(av[bi], bh[bj], acc[bi][bj], 0, 0, 0);
                if (BT == 2)
                    acc[bi][bj] = __builtin_amdgcn_mfma_f32_16x16x32_bf16(av[bi], bl[bj], acc[bi][bj], 0, 0, 0);
            }
        __builtin_amdgcn_s_setprio(0);
        // ---- 4. counted wait: only tile t+1's loads must land; t+2's keep flying ----
        if (step + 1 < nsteps) {
            if (step + 2 < nsteps)
                asm volatile("s_waitcnt vmcnt(%0)" :: "n"(NCH) : "memory");
            else
                asm volatile("s_waitcnt vmcnt(0)" ::: "memory");
            __builtin_amdgcn_s_barrier();
            __builtin_amdgcn_sched_barrier(0);
        }
        ro += BUF; if (ro == 3 * BUF) ro = 0;
        so += BUF; if (so == 3 * BUF) so = 0;
    }

    // ---- epilogue: acc -> LDS tile [128][132] -> coalesced 256B-row stores ----
    __syncthreads();               // all waves done with K-loop LDS before reuse
    u16* ct = lds;                 // 128 x 132 u16 = 33792 B
#pragma unroll
    for (int bj = 0; bj < 4; ++bj) {
        int cc = wn * 64 + bj * 16 + lane15;
        int gc = col0 + cc;
        float bv = (gc < NR1) ? (biasA ? biasA[gc] : 0.f)
                              : (biasB ? biasB[gc - NR1] : 0.f);
#pragma unroll
        for (int bi = 0; bi < 4; ++bi) {
            int rb = wm * 64 + bi * 16 + slot * 4;
#pragma unroll
            for (int qq = 0; qq < 4; ++qq) {
                float o = acc[bi][bj][qq] + bv;
                if (doRelu) o = fmaxf(o, 0.f);
                ct[(rb + qq) * 132 + cc] = bf16rn(o);
            }
        }
    }
    __syncthreads();
#pragma unroll
    for (int it = 0; it < 8; ++it) {
        int row = it * 16 + (tid >> 4);
        int c16 = (tid & 15) * 8;
        int gr = row0 + row;
        if (gr < M) {
            ushort8v vv = *(const ushort8v*)&ct[row * 132 + c16];
            *(ushort8v*)&Ch[(size_t)gr * ldc + col0 + c16] = vv;
        }
    }
}

// ---------------- GraphNorm stats (F = 256): 8 row-streams x 32 chunks / block ----
__global__ __launch_bounds__(256) void colstats2(const u16* __restrict__ H,
                                                 float* __restrict__ sums,
                                                 float* __restrict__ sqs, int N) {
    __shared__ float lsum[8][256];
    __shared__ float lsq[8][256];
    int t  = threadIdx.x;
    int g  = t >> 5;          // row-stream 0..7
    int cl = t & 31;          // feature chunk (8 feats)
    float s[8] = {}, q[8] = {};
    for (int row = blockIdx.x * 8 + g; row < N; row += gridDim.x * 8) {
        ushort8v v = *(const ushort8v*)&H[(size_t)row * 256 + (cl << 3)];
#pragma unroll
        for (int r = 0; r < 8; ++r) {
            float f = bf16tof(v[r]);
            s[r] += f;
            q[r] = fmaf(f, f, q[r]);
        }
    }
#pragma unroll
    for (int r = 0; r < 8; ++r) {
        lsum[g][(cl << 3) + r] = s[r];
        lsq[g][(cl << 3) + r]  = q[r];
    }
    __syncthreads();
    float ts = 0.f, tq = 0.f;
#pragma unroll
    for (int gg = 0; gg < 8; ++gg) { ts += lsum[gg][t]; tq += lsq[gg][t]; }
    atomicAdd(&sums[t], ts);
    atomicAdd(&sqs[t], tq);
}

__global__ void norm_prep(const float* __restrict__ sums, const float* __restrict__ sqs,
                          const float* __restrict__ gw, const float* __restrict__ gb,
                          const float* __restrict__ gms, float* __restrict__ scaleF,
                          float* __restrict__ shiftF, float invN) {
    int f = threadIdx.x;  // 256 threads
    float mu  = sums[f] * invN;
    float ex2 = sqs[f] * invN;
    float a   = gms[f] * mu;
    float var = ex2 - 2.f * a * mu + a * a;
    float inv = rsqrtf(var + 1e-5f);
    float sc  = gw[f] * inv;
    scaleF[f] = sc;
    shiftF[f] = gb[f] - a * sc;
}

__global__ __launch_bounds__(256) void norm_apply_sp(
    u16* __restrict__ H, const float* __restrict__ scaleF,
    const float* __restrict__ shiftF, int n8) {
    int i = blockIdx.x * 256 + threadIdx.x;
    if (i >= n8) return;
    int f0 = (i & 31) << 3;   // 256 feats = 32 chunks of 8
    ushort8v h = *(const ushort8v*)&H[(size_t)i * 8];
    ushort8v o;
#pragma unroll
    for (int r = 0; r < 8; ++r) {
        float v = fmaxf(fmaf(bf16tof(h[r]), scaleF[f0 + r], shiftF[f0 + r]), 0.f);
        o[r] = bf16rn(v);
    }
    *(ushort8v*)&H[(size_t)i * 8] = o;
}

// ---------------- launch ----------------
extern "C" void kernel_launch(void* const* d_in, const int* in_sizes, int n_in,
                              void* d_out, int out_size, void* d_ws, size_t ws_size,
                              hipStream_t stream) {
    const float* x   = (const float*)d_in[0];
    const int*   ei  = (const int*)d_in[1];
    const float* ea  = (const float*)d_in[2];
    const float* Wr1 = (const float*)d_in[3];
    const float* b1  = (const float*)d_in[4];
    const float* Wo1 = (const float*)d_in[5];
    const float* Wr2 = (const float*)d_in[6];
    const float* b2  = (const float*)d_in[7];
    const float* Wo2 = (const float*)d_in[8];
    const float* Wr3 = (const float*)d_in[9];
    const float* b3  = (const float*)d_in[10];
    const float* Wo3 = (const float*)d_in[11];
    const float* Wr4 = (const float*)d_in[12];
    const float* b4  = (const float*)d_in[13];
    const float* Wo4 = (const float*)d_in[14];
    const float* gw  = (const float*)d_in[15];
    const float* gb  = (const float*)d_in[16];
    const float* gms = (const float*)d_in[17];

    const int Nn = in_sizes[0] / F_IN;   // 50000
    const int E  = in_sizes[1] / 2;      // 400000
    const int* src = ei;
    const int* dst = ei + E;

    char* wp = (char*)d_ws;
    auto alloc = [&](size_t bytes) -> void* {
        void* p = (void*)wp;
        wp += (bytes + 255) & ~(size_t)255;
        return p;
    };
    int*   counts   = (int*)alloc((size_t)Nn * 4);
    int*   rowptr   = (int*)alloc((size_t)(Nn + 1) * 4);
    int*   fillhead = (int*)alloc((size_t)Nn * 4);
    int*   col      = (int*)alloc((size_t)E * 4);
    float* wv       = (float*)alloc((size_t)E * 4);
    float* stats    = (float*)alloc(1024 * 4);
    float* sums = stats, *sqs = stats + 256, *scaleF = stats + 512, *shiftF = stats + 768;
    int*   bsum     = (int*)alloc(256 * 4);
    int*   boff     = (int*)alloc(256 * 4);
    // weights: L1-L3 single bf16 plane, L4 fp24 hi/lo
    u16* wr1 = (u16*)alloc(2u * 256 * 144);
    u16* wo1 = (u16*)alloc(2u * 256 * 144);
    u16* wr2 = (u16*)alloc(2u * 512 * 256);
    u16* wo2 = (u16*)alloc(2u * 512 * 256);
    u16* wr3 = (u16*)alloc(2u * 256 * 512);
    u16* wo3 = (u16*)alloc(2u * 256 * 512);
    u16* wr4h = (u16*)alloc(2u * 128 * 256); u16* wr4l = (u16*)alloc(2u * 128 * 256);
    u16* wo4h = (u16*)alloc(2u * 128 * 256); u16* wo4l = (u16*)alloc(2u * 128 * 256);

    // ---- lifetime-packed region (u16 units), Nn*1168*2 B = 116.8 MB ----
    // live:  X[0,144) | AG[144,400) | H1[400,656) | H2[656,1168)
    // reuse: Y3 -> [0,512)    (X,AG,H1 dead after GEMM2)
    //        H3 -> [656,912)  (H2 dead after GEMM3)
    //        Y4 -> [0,256)    (Y3 dead after L3 aggregate)
    u16* big = (u16*)alloc((size_t)Nn * 1168 * 2);
    const size_t NS = (size_t)Nn;
    u16* Xb  = big;
    u16* AG  = big + NS * 144;
    u16* H1  = big + NS * 400;
    u16* H2  = big + NS * 656;
    u16* Y3  = big;
    u16* H3  = big + NS * 656;
    u16* Y4  = big;

    const int TB = 256;
    // CSR build (parallel scan)
    int nbScan = (Nn + SCB - 1) / SCB;
    zero_i32<<<(Nn + TB - 1) / TB, TB, 0, stream>>>(counts, Nn);
    count_edges<<<(E + TB - 1) / TB, TB, 0, stream>>>(dst, counts, E);
    scan_partial<<<nbScan, TB, 0, stream>>>(counts, rowptr, bsum, Nn);
    scan_tops<<<1, TB, 0, stream>>>(bsum, boff, nbScan);
    scan_add<<<(Nn + 1 + TB - 1) / TB, TB, 0, stream>>>(rowptr, fillhead, boff, Nn, E);
    fill_edges<<<(E + TB - 1) / TB, TB, 0, stream>>>(src, dst, ea, fillhead, col, wv, E);

    // conversions
    int nx = Nn * F_IN;
    conv_bf<<<(nx + 255) / 256, 256, 0, stream>>>(x, Xb, nx);
    struct BC { const float* s; u16* d; int n; } bc[6] = {
        {Wr1, wr1, 256 * 144}, {Wo1, wo1, 256 * 144},
        {Wr2, wr2, 512 * 256}, {Wo2, wo2, 512 * 256},
        {Wr3, wr3, 256 * 512}, {Wo3, wo3, 256 * 512}};
    for (int i = 0; i < 6; ++i)
        conv_bf<<<(bc[i].n + 255) / 256, 256, 0, stream>>>(bc[i].s, bc[i].d, bc[i].n);
    conv_hl<<<(128 * 256 + 255) / 256, 256, 0, stream>>>(Wr4, wr4h, wr4l, 128 * 256);
    conv_hl<<<(128 * 256 + 255) / 256, 256, 0, stream>>>(Wo4, wo4h, wo4l, 128 * 256);

    int mB = (Nn + GBM - 1) / GBM;              // 391
    int g3 = (((Nn + 2) / 3) + 3) / 4;          // 3 nodes/wave grids
    int g2 = (((Nn + 1) / 2) + 3) / 4;          // 2 nodes/wave grids
    int g4 = (((Nn + 3) / 4) + 3) / 4;          // 4 nodes/wave grids

    // Layer 1 (aggregate-first): AG = agg(X); H1 = relu([AG|X]*[Wr1|Wo1]^T + b1)
    aggregate_sp<18, 3, 0><<<g3, TB, 0, stream>>>(Xb, 144, rowptr, col, wv,
                                                  nullptr, AG, nullptr, 144, Nn);
    gemm7<true, 1><<<dim3(2, mB), 256, 0, stream>>>(AG, Xb, wr1, nullptr, wo1, nullptr,
                                                    b1, nullptr, H1,
                                                    Nn, 144, 256, 256, 1);
    // Layer 2 (aggregate-first): AG = agg(H1); H2 = relu([AG|H1]*[Wr2|Wo2]^T + b2)
    aggregate_sp<32, 2, 0><<<g2, TB, 0, stream>>>(H1, 256, rowptr, col, wv,
                                                  nullptr, AG, nullptr, 256, Nn);
    gemm7<true, 1><<<dim3(4, mB), 256, 0, stream>>>(AG, H1, wr2, nullptr, wo2, nullptr,
                                                    b2, nullptr, H2,
                                                    Nn, 256, 512, 512, 1);
    // Layer 3 (transform-first): Y3 = [H2*Wr3^T | H2*Wo3^T + b3]; H3 = agg(Yrel)+Yroot
    gemm7<false, 1><<<dim3(4, mB), 256, 0, stream>>>(H2, H2, wr3, nullptr, wo3, nullptr,
                                                     nullptr, b3, Y3,
                                                     Nn, 512, 256, 512, 0);
    aggregate_sp<32, 2, 1><<<g2, TB, 0, stream>>>(Y3, 512, rowptr, col, wv,
                                                  Y3 + 256, H3, nullptr, 256, Nn);
    // GraphNorm + relu in place on H3
    zero_f32<<<2, TB, 0, stream>>>(stats, 512);
    colstats2<<<800, TB, 0, stream>>>(H3, sums, sqs, Nn);
    norm_prep<<<1, 256, 0, stream>>>(sums, sqs, gw, gb, gms, scaleF, shiftF, 1.0f / Nn);
    norm_apply_sp<<<(Nn * 32 + TB - 1) / TB, TB, 0, stream>>>(H3, scaleF, shiftF, Nn * 32);
    // Layer 4 (transform-first, fp24 weights): Y4 = [H3*Wr4^T | H3*Wo4^T + b4] (bf16);
    // out = agg(Y4rel) + Y4root (f32)
    gemm7<false, 2><<<dim3(2, mB), 256, 0, stream>>>(H3, H3, wr4h, wr4l, wo4h, wo4l,
                                                     nullptr, b4, Y4,
                                                     Nn, 256, 128, 256, 0);
    aggregate_sp<16, 4, 2><<<g4, TB, 0, stream>>>(Y4, 256, rowptr, col, wv,
                                                  Y4 + 128, nullptr, (float*)d_out, 128, Nn);
}

// Round 17
// 371.251 us; speedup vs baseline: 1.1453x; 1.0169x over previous
//
#include <hip/hip_runtime.h>

#define F_IN 144
typedef __attribute__((ext_vector_type(8))) short short8v;
typedef __attribute__((ext_vector_type(8))) unsigned short ushort8v;
typedef __attribute__((ext_vector_type(4))) float f32x4;
typedef unsigned short u16;

// ---------------- bf16 helpers ----------------
__device__ __forceinline__ u16 bf16rn(float x) {
    union { float f; unsigned u; } a; a.f = x;
    return (u16)((a.u + 0x7FFFu + ((a.u >> 16) & 1u)) >> 16);
}
__device__ __forceinline__ float bf16tof(u16 h) {
    union { float f; unsigned u; } a; a.u = ((unsigned)h) << 16;
    return a.f;
}
__device__ __forceinline__ void gload_lds16(const u16* g, u16* s) {
    __builtin_amdgcn_global_load_lds(
        (const __attribute__((address_space(1))) void*)g,
        (__attribute__((address_space(3))) void*)s, 16, 0, 0);
}

// ---------------- utility ----------------
__global__ void zero_i32(int* __restrict__ p, int n) {
    int i = blockIdx.x * blockDim.x + threadIdx.x;
    if (i < n) p[i] = 0;
}
__global__ void zero_f32(float* __restrict__ p, int n) {
    int i = blockIdx.x * blockDim.x + threadIdx.x;
    if (i < n) p[i] = 0.f;
}
// f32 -> bf16 single plane
__global__ void conv_bf(const float* __restrict__ src, u16* __restrict__ d, int n) {
    int i = blockIdx.x * 256 + threadIdx.x;
    if (i < n) d[i] = bf16rn(src[i]);
}

// ---------------- CSR build ----------------
__global__ void count_edges(const int* __restrict__ dst, int* __restrict__ counts, int E) {
    int e = blockIdx.x * blockDim.x + threadIdx.x;
    if (e < E) atomicAdd(&counts[dst[e]], 1);
}

// 3-pass parallel exclusive scan (2048 elements per block)
#define SCB 2048
__global__ __launch_bounds__(256) void scan_partial(const int* __restrict__ counts,
                                                    int* __restrict__ rowptr,
                                                    int* __restrict__ bsum, int N) {
    __shared__ int ls[256];
    int t = threadIdx.x;
    int base = blockIdx.x * SCB + t * 8;
    int v[8]; int s = 0;
#pragma unroll
    for (int j = 0; j < 8; ++j) {
        int i = base + j;
        v[j] = (i < N) ? counts[i] : 0;
        s += v[j];
    }
    ls[t] = s;
    __syncthreads();
    for (int off = 1; off < 256; off <<= 1) {
        int x = (t >= off) ? ls[t - off] : 0;
        __syncthreads();
        ls[t] += x;
        __syncthreads();
    }
    int run = (t == 0) ? 0 : ls[t - 1];
#pragma unroll
    for (int j = 0; j < 8; ++j) {
        int i = base + j;
        if (i < N) rowptr[i] = run;
        run += v[j];
    }
    if (t == 255) bsum[blockIdx.x] = ls[255];
}

__global__ __launch_bounds__(256) void scan_tops(const int* __restrict__ bsum,
                                                 int* __restrict__ boff, int nb) {
    __shared__ int ls[256];
    int t = threadIdx.x;
    ls[t] = (t < nb) ? bsum[t] : 0;
    __syncthreads();
    for (int off = 1; off < 256; off <<= 1) {
        int x = (t >= off) ? ls[t - off] : 0;
        __syncthreads();
        ls[t] += x;
        __syncthreads();
    }
    boff[t] = (t == 0) ? 0 : ls[t - 1];   // exclusive block prefix
}

__global__ void scan_add(int* __restrict__ rowptr, int* __restrict__ fillhead,
                         const int* __restrict__ boff, int N, int E) {
    int i = blockIdx.x * 256 + threadIdx.x;
    if (i < N) {
        int r = rowptr[i] + boff[i >> 11];   // SCB = 2048 = 1<<11
        rowptr[i] = r;
        fillhead[i] = r;
    }
    if (i == N) rowptr[N] = E;
}

__global__ void fill_edges(const int* __restrict__ src, const int* __restrict__ dst,
                           const float* __restrict__ ea, int* __restrict__ fillhead,
                           int* __restrict__ col, float* __restrict__ wv, int E) {
    int e = blockIdx.x * blockDim.x + threadIdx.x;
    if (e < E) {
        int d = dst[e];
        int pos = atomicAdd(&fillhead[d], 1);
        col[pos] = src[e];
        wv[pos]  = ea[e];
    }
}

// ------------- single-plane aggregation, NPW nodes per wave -------------
// MODE 0: D = agg(S) (bf16). MODE 1: D = agg(S) + R (bf16). MODE 2: Df = agg(S) + R (f32).
// Edge loop unrolled x8 (8 independent 16B gathers in flight, 4 accumulator banks).
template<int NC, int NPW, int MODE>
__global__ __launch_bounds__(256) void aggregate_sp(
    const u16* __restrict__ S, int SS,
    const int* __restrict__ rowptr, const int* __restrict__ col,
    const float* __restrict__ wv,
    const u16* __restrict__ R,
    u16* __restrict__ D, float* __restrict__ Df, int FD, int N)
{
    int wav  = (int)((blockIdx.x * 256 + threadIdx.x) >> 6);
    int lane = threadIdx.x & 63;
    int sub  = lane / NC;
    int cl   = lane % NC;
    int wid  = wav * NPW + sub;
    if (sub >= NPW || wid >= N) return;
    float acc0[8] = {}, acc1[8] = {}, acc2[8] = {}, acc3[8] = {};
    int beg = rowptr[wid], end = rowptr[wid + 1];
    int e = beg;
    for (; e + 8 <= end; e += 8) {
        float w0 = wv[e],     w1 = wv[e + 1], w2 = wv[e + 2], w3 = wv[e + 3];
        float w4 = wv[e + 4], w5 = wv[e + 5], w6 = wv[e + 6], w7 = wv[e + 7];
        int c0 = col[e],     c1 = col[e + 1], c2 = col[e + 2], c3 = col[e + 3];
        int c4 = col[e + 4], c5 = col[e + 5], c6 = col[e + 6], c7 = col[e + 7];
        ushort8v v0 = *(const ushort8v*)&S[(size_t)c0 * SS + (cl << 3)];
        ushort8v v1 = *(const ushort8v*)&S[(size_t)c1 * SS + (cl << 3)];
        ushort8v v2 = *(const ushort8v*)&S[(size_t)c2 * SS + (cl << 3)];
        ushort8v v3 = *(const ushort8v*)&S[(size_t)c3 * SS + (cl << 3)];
        ushort8v v4 = *(const ushort8v*)&S[(size_t)c4 * SS + (cl << 3)];
        ushort8v v5 = *(const ushort8v*)&S[(size_t)c5 * SS + (cl << 3)];
        ushort8v v6 = *(const ushort8v*)&S[(size_t)c6 * SS + (cl << 3)];
        ushort8v v7 = *(const ushort8v*)&S[(size_t)c7 * SS + (cl << 3)];
#pragma unroll
        for (int r = 0; r < 8; ++r) {
            acc0[r] = fmaf(w0, bf16tof(v0[r]), acc0[r]);
            acc1[r] = fmaf(w1, bf16tof(v1[r]), acc1[r]);
            acc2[r] = fmaf(w2, bf16tof(v2[r]), acc2[r]);
            acc3[r] = fmaf(w3, bf16tof(v3[r]), acc3[r]);
            acc0[r] = fmaf(w4, bf16tof(v4[r]), acc0[r]);
            acc1[r] = fmaf(w5, bf16tof(v5[r]), acc1[r]);
            acc2[r] = fmaf(w6, bf16tof(v6[r]), acc2[r]);
            acc3[r] = fmaf(w7, bf16tof(v7[r]), acc3[r]);
        }
    }
    for (; e + 4 <= end; e += 4) {
        float w0 = wv[e], w1 = wv[e + 1], w2 = wv[e + 2], w3 = wv[e + 3];
        int   c0 = col[e], c1 = col[e + 1], c2 = col[e + 2], c3 = col[e + 3];
        ushort8v v0 = *(const ushort8v*)&S[(size_t)c0 * SS + (cl << 3)];
        ushort8v v1 = *(const ushort8v*)&S[(size_t)c1 * SS + (cl << 3)];
        ushort8v v2 = *(const ushort8v*)&S[(size_t)c2 * SS + (cl << 3)];
        ushort8v v3 = *(const ushort8v*)&S[(size_t)c3 * SS + (cl << 3)];
#pragma unroll
        for (int r = 0; r < 8; ++r) {
            acc0[r] = fmaf(w0, bf16tof(v0[r]), acc0[r]);
            acc1[r] = fmaf(w1, bf16tof(v1[r]), acc1[r]);
            acc2[r] = fmaf(w2, bf16tof(v2[r]), acc2[r]);
            acc3[r] = fmaf(w3, bf16tof(v3[r]), acc3[r]);
        }
    }
    for (; e < end; ++e) {
        float w0 = wv[e];
        ushort8v v0 = *(const ushort8v*)&S[(size_t)col[e] * SS + (cl << 3)];
#pragma unroll
        for (int r = 0; r < 8; ++r) acc0[r] = fmaf(w0, bf16tof(v0[r]), acc0[r]);
    }
#pragma unroll
    for (int r = 0; r < 8; ++r) acc0[r] += (acc1[r] + acc2[r]) + acc3[r];
    if (MODE >= 1) {
        ushort8v v = *(const ushort8v*)&R[(size_t)wid * SS + (cl << 3)];
#pragma unroll
        for (int r = 0; r < 8; ++r) acc0[r] += bf16tof(v[r]);
    }
    if (MODE == 2) {
        float* o = &Df[(size_t)wid * FD + (cl << 3)];
        *(float4*)o       = make_float4(acc0[0], acc0[1], acc0[2], acc0[3]);
        *(float4*)(o + 4) = make_float4(acc0[4], acc0[5], acc0[6], acc0[7]);
    } else {
        ushort8v o;
#pragma unroll
        for (int r = 0; r < 8; ++r) o[r] = bf16rn(acc0[r]);
        *(ushort8v*)&D[(size_t)wid * FD + (cl << 3)] = o;
    }
}

// ------- gemm7: A bf16, B bf16, 128x128, 3-deep counted-vmcnt pipeline -------
// C = A*B^T (+bias), bf16 out via LDS-coalesced epilogue.
// DUALK=true: A=[A1|A2], B=[B1|B2] along K (KK=2*K1).
// DUALK=false: A=A1 (KK=K1); B rows r<NR1 -> B1[r] else B2[r-NR1] (NR1 % 128 == 0).
// 4 waves. LDS = 3 x 16KB buffers. Per step: ds_read frags of buf[t%3] -> issue
// stage of tile t+2 into buf[(t+2)%3] -> MFMA (setprio wrap) -> s_waitcnt
// vmcnt(NCH) (tile t+1 landed; t+2 in flight) + raw s_barrier + sched_barrier(0).
// Bijective XCD-chunk swizzle (m204). Epilogue: acc -> LDS [128][132] -> 256B rows.
#define GBM 128
#define GBN 128

template<bool DUALK>
__global__ __launch_bounds__(256) void gemm7(
    const u16* __restrict__ A1, const u16* __restrict__ A2,
    const u16* __restrict__ B1, const u16* __restrict__ B2,
    const float* __restrict__ biasA, const float* __restrict__ biasB,
    u16* __restrict__ Ch,
    int M, int K1, int NR1, int ldc, int doRelu)
{
    constexpr int NCH = 4;                // staged 16B chunks per thread per tile
    constexpr int BUF = 8192;             // u16 per buffer (A 4096 + B 4096)
    __shared__ u16 lds[3 * BUF];          // 48 KB

    const int tid = threadIdx.x;
    const int l = tid & 63, w = tid >> 6;
    const int wm = w >> 1, wn = w & 1;
    const int lane15 = l & 15, slot = l >> 4;

    // ---- bijective XCD-chunk swizzle (m204) ----
    const int nwg = gridDim.x * gridDim.y;
    const int bid = blockIdx.y * gridDim.x + blockIdx.x;
    const int q = nwg >> 3, r8 = nwg & 7;
    const int xcd = bid & 7, v = bid >> 3;
    const int sw = (xcd < r8) ? xcd * (q + 1) + v : r8 * (q + 1) + (xcd - r8) * q + v;
    const int row0 = (sw / gridDim.x) * GBM;
    const int col0 = (sw % gridDim.x) * GBN;

    const int KK = DUALK ? 2 * K1 : K1;
    const int nsteps = KK / 32;

    // ---- staging precompute: 2 planes x 512 chunks, 4 per thread ----
    const u16* q1[NCH]; const u16* q2[NCH]; int lim[NCH]; int dstoff[NCH];
#pragma unroll
    for (int i = 0; i < NCH; ++i) {
        int idx0  = i * 256 + (tid & ~63);      // wave-uniform
        int p     = idx0 >> 9;                  // plane 0:A 1:B
        int cbase = idx0 & 511;
        int c  = cbase + l;                     // per-lane chunk
        int rw = c >> 2, ch = c & 3;
        int cpk = (ch ^ ((rw >> 1) & 3)) << 3;  // swizzled source k-offset (u16)
        lim[i]    = K1 - cpk;
        dstoff[i] = (p << 12) + (cbase << 3);
        const u16 *b1, *b2; int g;
        if (p == 0) {
            b1 = A1; b2 = A2 - K1;
            g = min(row0 + rw, M - 1);
        } else {
            if (DUALK) { b1 = B1; b2 = B2 - K1; g = col0 + rw; }
            else {
                bool sec = (col0 >= NR1);
                b1 = sec ? B2 : B1; b2 = b1;
                g = col0 + rw - (sec ? NR1 : 0);
            }
        }
        q1[i] = b1 + g * K1 + cpk;
        q2[i] = b2 + g * K1 + cpk;
    }

    auto stage = [&](u16* base, int kk0) {
#pragma unroll
        for (int i = 0; i < NCH; ++i) {
            const u16* s = (DUALK && kk0 >= lim[i]) ? q2[i] : q1[i];
            gload_lds16(s + kk0, base + dstoff[i]);
        }
    };

    f32x4 acc[4][4] = {};

    // ---- prologue: stage tiles 0 and 1 ----
    stage(lds, 0);
    if (nsteps > 1) {
        stage(lds + BUF, 32);
        asm volatile("s_waitcnt vmcnt(%0)" :: "n"(NCH) : "memory");  // tile0 landed
    } else {
        asm volatile("s_waitcnt vmcnt(0)" ::: "memory");
    }
    __builtin_amdgcn_s_barrier();
    __builtin_amdgcn_sched_barrier(0);

    int ro = 0, so = 2 * BUF;   // read offset (t%3), stage offset ((t+2)%3)
    for (int step = 0; step < nsteps; ++step) {
        const u16* cb = lds + ro;
        // ---- 1. ds_read fragments of current tile ----
        short8v av[4], bh[4];
#pragma unroll
        for (int bi = 0; bi < 4; ++bi) {
            int r = wm * 64 + bi * 16 + lane15;
            int j = slot ^ ((r >> 1) & 3);
            av[bi] = *(const short8v*)&cb[r * 32 + j * 8];
        }
#pragma unroll
        for (int bj = 0; bj < 4; ++bj) {
            int c = wn * 64 + bj * 16 + lane15;
            int j = slot ^ ((c >> 1) & 3);
            bh[bj] = *(const short8v*)&cb[4096 + c * 32 + j * 8];
        }
        // ---- 2. issue stage of tile t+2 (stays in flight across the barrier) ----
        if (step + 2 < nsteps) stage(lds + so, (step + 2) * 32);
        // ---- 3. MFMA (T5 setprio wrap) ----
        __builtin_amdgcn_s_setprio(1);
#pragma unroll
        for (int bj = 0; bj < 4; ++bj)
#pragma unroll
            for (int bi = 0; bi < 4; ++bi)
                acc[bi][bj] = __builtin_amdgcn_mfma_f32_16x16x32_bf16(av[bi], bh[bj], acc[bi][bj], 0, 0, 0);
        __builtin_amdgcn_s_setprio(0);
        // ---- 4. counted wait: only tile t+1's loads must land; t+2's keep flying ----
        if (step + 1 < nsteps) {
            if (step + 2 < nsteps)
                asm volatile("s_waitcnt vmcnt(%0)" :: "n"(NCH) : "memory");
            else
                asm volatile("s_waitcnt vmcnt(0)" ::: "memory");
            __builtin_amdgcn_s_barrier();
            __builtin_amdgcn_sched_barrier(0);
        }
        ro += BUF; if (ro == 3 * BUF) ro = 0;
        so += BUF; if (so == 3 * BUF) so = 0;
    }

    // ---- epilogue: acc -> LDS tile [128][132] -> coalesced 256B-row stores ----
    __syncthreads();               // all waves done with K-loop LDS before reuse
    u16* ct = lds;                 // 128 x 132 u16 = 33792 B
#pragma unroll
    for (int bj = 0; bj < 4; ++bj) {
        int cc = wn * 64 + bj * 16 + lane15;
        int gc = col0 + cc;
        float bv = (gc < NR1) ? (biasA ? biasA[gc] : 0.f)
                              : (biasB ? biasB[gc - NR1] : 0.f);
#pragma unroll
        for (int bi = 0; bi < 4; ++bi) {
            int rb = wm * 64 + bi * 16 + slot * 4;
#pragma unroll
            for (int qq = 0; qq < 4; ++qq) {
                float o = acc[bi][bj][qq] + bv;
                if (doRelu) o = fmaxf(o, 0.f);
                ct[(rb + qq) * 132 + cc] = bf16rn(o);
            }
        }
    }
    __syncthreads();
#pragma unroll
    for (int it = 0; it < 8; ++it) {
        int row = it * 16 + (tid >> 4);
        int c16 = (tid & 15) * 8;
        int gr = row0 + row;
        if (gr < M) {
            ushort8v vv = *(const ushort8v*)&ct[row * 132 + c16];
            *(ushort8v*)&Ch[(size_t)gr * ldc + col0 + c16] = vv;
        }
    }
}

// ---------------- GraphNorm stats (F = 256): 8 row-streams x 32 chunks / block ----
__global__ __launch_bounds__(256) void colstats2(const u16* __restrict__ H,
                                                 float* __restrict__ sums,
                                                 float* __restrict__ sqs, int N) {
    __shared__ float lsum[8][256];
    __shared__ float lsq[8][256];
    int t  = threadIdx.x;
    int g  = t >> 5;          // row-stream 0..7
    int cl = t & 31;          // feature chunk (8 feats)
    float s[8] = {}, q[8] = {};
    for (int row = blockIdx.x * 8 + g; row < N; row += gridDim.x * 8) {
        ushort8v v = *(const ushort8v*)&H[(size_t)row * 256 + (cl << 3)];
#pragma unroll
        for (int r = 0; r < 8; ++r) {
            float f = bf16tof(v[r]);
            s[r] += f;
            q[r] = fmaf(f, f, q[r]);
        }
    }
#pragma unroll
    for (int r = 0; r < 8; ++r) {
        lsum[g][(cl << 3) + r] = s[r];
        lsq[g][(cl << 3) + r]  = q[r];
    }
    __syncthreads();
    float ts = 0.f, tq = 0.f;
#pragma unroll
    for (int gg = 0; gg < 8; ++gg) { ts += lsum[gg][t]; tq += lsq[gg][t]; }
    atomicAdd(&sums[t], ts);
    atomicAdd(&sqs[t], tq);
}

__global__ void norm_prep(const float* __restrict__ sums, const float* __restrict__ sqs,
                          const float* __restrict__ gw, const float* __restrict__ gb,
                          const float* __restrict__ gms, float* __restrict__ scaleF,
                          float* __restrict__ shiftF, float invN) {
    int f = threadIdx.x;  // 256 threads
    float mu  = sums[f] * invN;
    float ex2 = sqs[f] * invN;
    float a   = gms[f] * mu;
    float var = ex2 - 2.f * a * mu + a * a;
    float inv = rsqrtf(var + 1e-5f);
    float sc  = gw[f] * inv;
    scaleF[f] = sc;
    shiftF[f] = gb[f] - a * sc;
}

__global__ __launch_bounds__(256) void norm_apply_sp(
    u16* __restrict__ H, const float* __restrict__ scaleF,
    const float* __restrict__ shiftF, int n8) {
    int i = blockIdx.x * 256 + threadIdx.x;
    if (i >= n8) return;
    int f0 = (i & 31) << 3;   // 256 feats = 32 chunks of 8
    ushort8v h = *(const ushort8v*)&H[(size_t)i * 8];
    ushort8v o;
#pragma unroll
    for (int r = 0; r < 8; ++r) {
        float v = fmaxf(fmaf(bf16tof(h[r]), scaleF[f0 + r], shiftF[f0 + r]), 0.f);
        o[r] = bf16rn(v);
    }
    *(ushort8v*)&H[(size_t)i * 8] = o;
}

// ---------------- launch ----------------
extern "C" void kernel_launch(void* const* d_in, const int* in_sizes, int n_in,
                              void* d_out, int out_size, void* d_ws, size_t ws_size,
                              hipStream_t stream) {
    const float* x   = (const float*)d_in[0];
    const int*   ei  = (const int*)d_in[1];
    const float* ea  = (const float*)d_in[2];
    const float* Wr1 = (const float*)d_in[3];
    const float* b1  = (const float*)d_in[4];
    const float* Wo1 = (const float*)d_in[5];
    const float* Wr2 = (const float*)d_in[6];
    const float* b2  = (const float*)d_in[7];
    const float* Wo2 = (const float*)d_in[8];
    const float* Wr3 = (const float*)d_in[9];
    const float* b3  = (const float*)d_in[10];
    const float* Wo3 = (const float*)d_in[11];
    const float* Wr4 = (const float*)d_in[12];
    const float* b4  = (const float*)d_in[13];
    const float* Wo4 = (const float*)d_in[14];
    const float* gw  = (const float*)d_in[15];
    const float* gb  = (const float*)d_in[16];
    const float* gms = (const float*)d_in[17];

    const int Nn = in_sizes[0] / F_IN;   // 50000
    const int E  = in_sizes[1] / 2;      // 400000
    const int* src = ei;
    const int* dst = ei + E;

    char* wp = (char*)d_ws;
    auto alloc = [&](size_t bytes) -> void* {
        void* p = (void*)wp;
        wp += (bytes + 255) & ~(size_t)255;
        return p;
    };
    int*   counts   = (int*)alloc((size_t)Nn * 4);
    int*   rowptr   = (int*)alloc((size_t)(Nn + 1) * 4);
    int*   fillhead = (int*)alloc((size_t)Nn * 4);
    int*   col      = (int*)alloc((size_t)E * 4);
    float* wv       = (float*)alloc((size_t)E * 4);
    float* stats    = (float*)alloc(1024 * 4);
    float* sums = stats, *sqs = stats + 256, *scaleF = stats + 512, *shiftF = stats + 768;
    int*   bsum     = (int*)alloc(256 * 4);
    int*   boff     = (int*)alloc(256 * 4);
    // weights: all single bf16 plane
    u16* wr1 = (u16*)alloc(2u * 256 * 144);
    u16* wo1 = (u16*)alloc(2u * 256 * 144);
    u16* wr2 = (u16*)alloc(2u * 512 * 256);
    u16* wo2 = (u16*)alloc(2u * 512 * 256);
    u16* wr3 = (u16*)alloc(2u * 256 * 512);
    u16* wo3 = (u16*)alloc(2u * 256 * 512);
    u16* wr4 = (u16*)alloc(2u * 128 * 256);
    u16* wo4 = (u16*)alloc(2u * 128 * 256);

    // ---- lifetime-packed region (u16 units), Nn*1168*2 B = 116.8 MB ----
    // live:  X[0,144) | AG[144,400) | H1[400,656) | H2[656,1168)
    // reuse: Y3 -> [0,512)    (X,AG,H1 dead after GEMM2)
    //        H3 -> [656,912)  (H2 dead after GEMM3)
    //        Y4 -> [0,256)    (Y3 dead after L3 aggregate)
    u16* big = (u16*)alloc((size_t)Nn * 1168 * 2);
    const size_t NS = (size_t)Nn;
    u16* Xb  = big;
    u16* AG  = big + NS * 144;
    u16* H1  = big + NS * 400;
    u16* H2  = big + NS * 656;
    u16* Y3  = big;
    u16* H3  = big + NS * 656;
    u16* Y4  = big;

    const int TB = 256;
    // CSR build (parallel scan)
    int nbScan = (Nn + SCB - 1) / SCB;
    zero_i32<<<(Nn + TB - 1) / TB, TB, 0, stream>>>(counts, Nn);
    count_edges<<<(E + TB - 1) / TB, TB, 0, stream>>>(dst, counts, E);
    scan_partial<<<nbScan, TB, 0, stream>>>(counts, rowptr, bsum, Nn);
    scan_tops<<<1, TB, 0, stream>>>(bsum, boff, nbScan);
    scan_add<<<(Nn + 1 + TB - 1) / TB, TB, 0, stream>>>(rowptr, fillhead, boff, Nn, E);
    fill_edges<<<(E + TB - 1) / TB, TB, 0, stream>>>(src, dst, ea, fillhead, col, wv, E);

    // conversions
    int nx = Nn * F_IN;
    conv_bf<<<(nx + 255) / 256, 256, 0, stream>>>(x, Xb, nx);
    struct BC { const float* s; u16* d; int n; } bc[8] = {
        {Wr1, wr1, 256 * 144}, {Wo1, wo1, 256 * 144},
        {Wr2, wr2, 512 * 256}, {Wo2, wo2, 512 * 256},
        {Wr3, wr3, 256 * 512}, {Wo3, wo3, 256 * 512},
        {Wr4, wr4, 128 * 256}, {Wo4, wo4, 128 * 256}};
    for (int i = 0; i < 8; ++i)
        conv_bf<<<(bc[i].n + 255) / 256, 256, 0, stream>>>(bc[i].s, bc[i].d, bc[i].n);

    int mB = (Nn + GBM - 1) / GBM;              // 391
    int g3 = (((Nn + 2) / 3) + 3) / 4;          // 3 nodes/wave grids
    int g2 = (((Nn + 1) / 2) + 3) / 4;          // 2 nodes/wave grids
    int g4 = (((Nn + 3) / 4) + 3) / 4;          // 4 nodes/wave grids

    // Layer 1 (aggregate-first): AG = agg(X); H1 = relu([AG|X]*[Wr1|Wo1]^T + b1)
    aggregate_sp<18, 3, 0><<<g3, TB, 0, stream>>>(Xb, 144, rowptr, col, wv,
                                                  nullptr, AG, nullptr, 144, Nn);
    gemm7<true><<<dim3(2, mB), 256, 0, stream>>>(AG, Xb, wr1, wo1,
                                                 b1, nullptr, H1,
                                                 Nn, 144, 256, 256, 1);
    // Layer 2 (aggregate-first): AG = agg(H1); H2 = relu([AG|H1]*[Wr2|Wo2]^T + b2)
    aggregate_sp<32, 2, 0><<<g2, TB, 0, stream>>>(H1, 256, rowptr, col, wv,
                                                  nullptr, AG, nullptr, 256, Nn);
    gemm7<true><<<dim3(4, mB), 256, 0, stream>>>(AG, H1, wr2, wo2,
                                                 b2, nullptr, H2,
                                                 Nn, 256, 512, 512, 1);
    // Layer 3 (transform-first): Y3 = [H2*Wr3^T | H2*Wo3^T + b3]; H3 = agg(Yrel)+Yroot
    gemm7<false><<<dim3(4, mB), 256, 0, stream>>>(H2, H2, wr3, wo3,
                                                  nullptr, b3, Y3,
                                                  Nn, 512, 256, 512, 0);
    aggregate_sp<32, 2, 1><<<g2, TB, 0, stream>>>(Y3, 512, rowptr, col, wv,
                                                  Y3 + 256, H3, nullptr, 256, Nn);
    // GraphNorm + relu in place on H3
    zero_f32<<<2, TB, 0, stream>>>(stats, 512);
    colstats2<<<800, TB, 0, stream>>>(H3, sums, sqs, Nn);
    norm_prep<<<1, 256, 0, stream>>>(sums, sqs, gw, gb, gms, scaleF, shiftF, 1.0f / Nn);
    norm_apply_sp<<<(Nn * 32 + TB - 1) / TB, TB, 0, stream>>>(H3, scaleF, shiftF, Nn * 32);
    // Layer 4 (transform-first, bf16 weights): Y4 = [H3*Wr4^T | H3*Wo4^T + b4] (bf16);
    // out = agg(Y4rel) + Y4root (f32)
    gemm7<false><<<dim3(2, mB), 256, 0, stream>>>(H3, H3, wr4, wo4,
                                                  nullptr, b4, Y4,
                                                  Nn, 256, 128, 256, 0);
    aggregate_sp<16, 4, 2><<<g4, TB, 0, stream>>>(Y4, 256, rowptr, col, wv,
                                                  Y4 + 128, nullptr, (float*)d_out, 128, Nn);
}